// Round 1
// baseline (124.499 us; speedup 1.0000x reference)
//
#include <hip/hip_runtime.h>

#define N_GAUSS 16384
#define SPLIT   16
#define GPS     (N_GAUSS / SPLIT)   // 1024 gaussians per split
#define TILE    64
#define NPIX    (TILE * TILE)       // 4096 pixels per image
#define EPS     1e-5f

// Per-gaussian precompute: pm = (mx, my, mz, kg), cl = (r, g, b, |m|^2)
// kg = -0.5 / (sigma^2 + eps), sigma = sqrt(mean(diag(cov))) as in reference.
__global__ void precompute_kernel(const float* __restrict__ means,
                                  const float* __restrict__ covs,
                                  const float* __restrict__ colors,
                                  float4* __restrict__ pm,
                                  float4* __restrict__ cl) {
    int g = blockIdx.x * blockDim.x + threadIdx.x;
    if (g >= N_GAUSS) return;
    float mx = means[3 * g + 0];
    float my = means[3 * g + 1];
    float mz = means[3 * g + 2];
    const float* c = covs + 9 * g;
    float s2  = (c[0] + c[4] + c[8]) * (1.0f / 3.0f);
    float sig = sqrtf(s2);                    // match reference's sqrt->square
    float kg  = -0.5f / (sig * sig + EPS);
    pm[g] = make_float4(mx, my, mz, kg);
    float mm = mx * mx + my * my + mz * mz;
    cl[g] = make_float4(colors[3 * g + 0], colors[3 * g + 1], colors[3 * g + 2], mm);
}

// grid: (NPIX/256, SPLIT, n_imgs), block: 256. One thread = one pixel,
// looping over this block's 1024-gaussian LDS-staged slice.
__global__ __launch_bounds__(256) void render_kernel(
        const float4* __restrict__ pm,
        const float4* __restrict__ cl,
        const float*  __restrict__ intr,
        const float*  __restrict__ extr,
        const int*    __restrict__ img_ids,
        float4*       __restrict__ partial,
        int n_imgs) {
    __shared__ float4 s_pm[GPS];
    __shared__ float4 s_cl[GPS];

    const int tid   = threadIdx.x;
    const int split = blockIdx.y;
    const int img   = blockIdx.z;
    const int gbase = split * GPS;

    #pragma unroll
    for (int k = 0; k < GPS / 256; k++) {
        s_pm[tid + k * 256] = pm[gbase + tid + k * 256];
        s_cl[tid + k * 256] = cl[gbase + tid + k * 256];
    }

    const int cam = img_ids[img];
    const float* I = intr + 4 * cam;
    const float* E = extr + 16 * cam;
    const float fx = I[0], fy = I[1], cx = I[2], cy = I[3];

    const int pixel = blockIdx.x * 256 + tid;
    const int row = pixel >> 6;
    const int col = pixel & 63;

    // dirs = [(col-cx)/fx, -(row-cy)/fy, -1]; rays_d = R * dirs (R row-major)
    const float d0 = ((float)col - cx) / fx;
    const float d1 = -(((float)row) - cy) / fy;
    const float d2 = -1.0f;
    const float rdx = d0 * E[0] + d1 * E[1] + d2 * E[2];
    const float rdy = d0 * E[4] + d1 * E[5] + d2 * E[6];
    const float rdz = d0 * E[8] + d1 * E[9] + d2 * E[10];
    const float ox = E[3], oy = E[7], oz = E[11];

    // |pdiff|^2 = |m-o|^2 + t^2*(|d|^2 - 2),  t = (m-o).d
    // |m-o|^2 = |m|^2 - 2 m.o + |o|^2
    const float dd2 = rdx * rdx + rdy * rdy + rdz * rdz - 2.0f;
    const float oo  = ox * ox + oy * oy + oz * oz;
    const float mod = -(ox * rdx + oy * rdy + oz * rdz);  // -(o.d)
    const float oxn = -2.0f * ox, oyn = -2.0f * oy, ozn = -2.0f * oz;

    __syncthreads();

    float wsum = 0.0f, cr = 0.0f, cg = 0.0f, cb = 0.0f;
    #pragma unroll 4
    for (int g = 0; g < GPS; g++) {
        const float4 m = s_pm[g];
        const float4 c = s_cl[g];
        const float t  = fmaf(m.x, rdx, fmaf(m.y, rdy, fmaf(m.z, rdz, mod)));
        const float n2 = fmaf(m.x, oxn, fmaf(m.y, oyn, fmaf(m.z, ozn, oo))) + c.w;
        const float dist2 = fmaf(t * t, dd2, n2);
        const float w = __expf(m.w * dist2);
        wsum += w;
        cr = fmaf(w, c.x, cr);
        cg = fmaf(w, c.y, cg);
        cb = fmaf(w, c.z, cb);
    }

    const int idx = img * NPIX + pixel;                // 0 .. n_imgs*NPIX-1
    partial[split * (n_imgs * NPIX) + idx] = make_float4(wsum, cr, cg, cb);
}

__global__ void reduce_kernel(const float4* __restrict__ partial,
                              float* __restrict__ out,
                              int n_imgs) {
    const int idx = blockIdx.x * blockDim.x + threadIdx.x;
    const int total = n_imgs * NPIX;
    if (idx >= total) return;
    float w = 0.0f, r = 0.0f, g = 0.0f, b = 0.0f;
    #pragma unroll
    for (int s = 0; s < SPLIT; s++) {
        const float4 p = partial[s * total + idx];
        w += p.x; r += p.y; g += p.z; b += p.w;
    }
    const float inv = 1.0f / (w + EPS);
    const int img = idx >> 12;        // / NPIX
    const int pix = idx & (NPIX - 1);
    out[(img * 3 + 0) * NPIX + pix] = r * inv;
    out[(img * 3 + 1) * NPIX + pix] = g * inv;
    out[(img * 3 + 2) * NPIX + pix] = b * inv;
}

extern "C" void kernel_launch(void* const* d_in, const int* in_sizes, int n_in,
                              void* d_out, int out_size, void* d_ws, size_t ws_size,
                              hipStream_t stream) {
    const float* means   = (const float*)d_in[0];
    const float* covs    = (const float*)d_in[1];
    const float* colors  = (const float*)d_in[2];
    const float* intr    = (const float*)d_in[3];
    const float* extr    = (const float*)d_in[4];
    const int*   img_ids = (const int*)d_in[5];
    float* out = (float*)d_out;
    const int n_imgs = in_sizes[5];

    // ws layout: pm[N_GAUSS] | cl[N_GAUSS] | partial[SPLIT * n_imgs * NPIX]
    float4* pm      = (float4*)d_ws;
    float4* cl      = pm + N_GAUSS;
    float4* partial = cl + N_GAUSS;

    precompute_kernel<<<(N_GAUSS + 255) / 256, 256, 0, stream>>>(
        means, covs, colors, pm, cl);

    dim3 grid(NPIX / 256, SPLIT, n_imgs);
    render_kernel<<<grid, 256, 0, stream>>>(pm, cl, intr, extr, img_ids, partial, n_imgs);

    const int total = n_imgs * NPIX;
    reduce_kernel<<<(total + 255) / 256, 256, 0, stream>>>(partial, out, n_imgs);
}

// Round 2
// 123.764 us; speedup vs baseline: 1.0059x; 1.0059x over previous
//
#include <hip/hip_runtime.h>

#define N_GAUSS 16384
#define SPLIT   32
#define GPS     (N_GAUSS / SPLIT)   // 512 gaussians per split
#define TILE    64
#define NPIX    (TILE * TILE)       // 4096 pixels per image
#define EPS     1e-5f

// Per-(image, gaussian) precompute, packed 8 floats:
//   A = (mx, my, mz, kg)        kg = -0.5/(sigma^2+eps)
//   B = (r, g, b, e0)           e0 = kg * |m - o_img|^2
// so  arg = kg*dist2 = fma(kg*t*t, dd2, e0)  with per-pixel dd2 = |d|^2 - 2.
__global__ void precompute_kernel(const float* __restrict__ means,
                                  const float* __restrict__ covs,
                                  const float* __restrict__ colors,
                                  const float* __restrict__ extr,
                                  const int*   __restrict__ img_ids,
                                  float4* __restrict__ AB,
                                  int n_imgs) {
    int idx = blockIdx.x * blockDim.x + threadIdx.x;
    if (idx >= n_imgs * N_GAUSS) return;
    const int img = idx / N_GAUSS;
    const int g   = idx - img * N_GAUSS;

    const float mx = means[3 * g + 0];
    const float my = means[3 * g + 1];
    const float mz = means[3 * g + 2];
    const float* c = covs + 9 * g;
    const float s2  = (c[0] + c[4] + c[8]) * (1.0f / 3.0f);
    const float sig = sqrtf(s2);                 // match reference rounding
    const float kg  = -0.5f / (sig * sig + EPS);

    const int cam = img_ids[img];
    const float* E = extr + 16 * cam;
    const float ox = E[3], oy = E[7], oz = E[11];
    const float ux = mx - ox, uy = my - oy, uz = mz - oz;
    const float n2c = ux * ux + uy * uy + uz * uz;

    AB[2 * idx + 0] = make_float4(mx, my, mz, kg);
    AB[2 * idx + 1] = make_float4(colors[3 * g + 0], colors[3 * g + 1],
                                  colors[3 * g + 2], kg * n2c);
}

// grid: (NPIX/256, SPLIT, n_imgs), block 256. One thread = one pixel.
// Gaussian data read at wave-uniform addresses (scalar-load path), no LDS.
__global__ __launch_bounds__(256) void render_kernel(
        const float4* __restrict__ AB,
        const float*  __restrict__ intr,
        const float*  __restrict__ extr,
        const int*    __restrict__ img_ids,
        float4*       __restrict__ partial,
        int n_imgs) {
    const int tid   = threadIdx.x;
    const int split = blockIdx.y;
    const int img   = blockIdx.z;

    const int cam = img_ids[img];
    const float* I = intr + 4 * cam;
    const float* E = extr + 16 * cam;
    const float fx = I[0], fy = I[1], cx = I[2], cy = I[3];

    const int pixel = blockIdx.x * 256 + tid;
    const int row = pixel >> 6;
    const int col = pixel & 63;

    const float d0 = ((float)col - cx) / fx;
    const float d1 = -(((float)row) - cy) / fy;
    const float d2 = -1.0f;
    const float rdx = d0 * E[0] + d1 * E[1] + d2 * E[2];
    const float rdy = d0 * E[4] + d1 * E[5] + d2 * E[6];
    const float rdz = d0 * E[8] + d1 * E[9] + d2 * E[10];
    const float ox = E[3], oy = E[7], oz = E[11];

    const float dd2 = rdx * rdx + rdy * rdy + rdz * rdz - 2.0f;
    const float mod = -(ox * rdx + oy * rdy + oz * rdz);   // -(o.d)

    const float4* __restrict__ base = AB + 2 * (img * N_GAUSS + split * GPS);

    float wsum = 0.0f, cr = 0.0f, cg = 0.0f, cb = 0.0f;
    #pragma unroll 4
    for (int g = 0; g < GPS; g++) {
        const float4 a = base[2 * g + 0];
        const float4 b = base[2 * g + 1];
        const float t  = fmaf(a.x, rdx, fmaf(a.y, rdy, fmaf(a.z, rdz, mod)));
        const float q  = a.w * (t * t);
        const float w  = __expf(fmaf(q, dd2, b.w));
        wsum += w;
        cr = fmaf(w, b.x, cr);
        cg = fmaf(w, b.y, cg);
        cb = fmaf(w, b.z, cb);
    }

    const int idx = img * NPIX + pixel;
    partial[split * (n_imgs * NPIX) + idx] = make_float4(wsum, cr, cg, cb);
}

__global__ void reduce_kernel(const float4* __restrict__ partial,
                              float* __restrict__ out,
                              int n_imgs) {
    const int idx = blockIdx.x * blockDim.x + threadIdx.x;
    const int total = n_imgs * NPIX;
    if (idx >= total) return;
    float w = 0.0f, r = 0.0f, g = 0.0f, b = 0.0f;
    #pragma unroll 8
    for (int s = 0; s < SPLIT; s++) {
        const float4 p = partial[s * total + idx];
        w += p.x; r += p.y; g += p.z; b += p.w;
    }
    const float inv = 1.0f / (w + EPS);
    const int img = idx >> 12;        // / NPIX
    const int pix = idx & (NPIX - 1);
    out[(img * 3 + 0) * NPIX + pix] = r * inv;
    out[(img * 3 + 1) * NPIX + pix] = g * inv;
    out[(img * 3 + 2) * NPIX + pix] = b * inv;
}

extern "C" void kernel_launch(void* const* d_in, const int* in_sizes, int n_in,
                              void* d_out, int out_size, void* d_ws, size_t ws_size,
                              hipStream_t stream) {
    const float* means   = (const float*)d_in[0];
    const float* covs    = (const float*)d_in[1];
    const float* colors  = (const float*)d_in[2];
    const float* intr    = (const float*)d_in[3];
    const float* extr    = (const float*)d_in[4];
    const int*   img_ids = (const int*)d_in[5];
    float* out = (float*)d_out;
    const int n_imgs = in_sizes[5];

    // ws layout: AB[2 * n_imgs * N_GAUSS] | partial[SPLIT * n_imgs * NPIX]
    float4* AB      = (float4*)d_ws;
    float4* partial = AB + 2 * n_imgs * N_GAUSS;

    const int npre = n_imgs * N_GAUSS;
    precompute_kernel<<<(npre + 255) / 256, 256, 0, stream>>>(
        means, covs, colors, extr, img_ids, AB, n_imgs);

    dim3 grid(NPIX / 256, SPLIT, n_imgs);
    render_kernel<<<grid, 256, 0, stream>>>(AB, intr, extr, img_ids, partial, n_imgs);

    const int total = n_imgs * NPIX;
    reduce_kernel<<<(total + 255) / 256, 256, 0, stream>>>(partial, out, n_imgs);
}

// Round 3
// 117.015 us; speedup vs baseline: 1.0640x; 1.0577x over previous
//
#include <hip/hip_runtime.h>

#define N_GAUSS 16384
#define SPLIT   64
#define GPS     (N_GAUSS / SPLIT)   // 256 gaussians per split
#define TILE    64
#define NPIX    (TILE * TILE)       // 4096 pixels per image
#define EPS     1e-5f
#define LOG2E   1.44269504088896340736f

// Per-(image, gaussian) precompute, packed 8 floats:
//   A = (mx, my, mz, kg2)       kg2 = log2(e) * -0.5/(sigma^2+eps)
//   B = (r, g, b, e0)           e0  = kg2 * |m - o_img|^2
// so  w = exp2( fma(kg2*t*t, dd2, e0) )  with per-pixel dd2 = |d|^2 - 2.
__global__ void precompute_kernel(const float* __restrict__ means,
                                  const float* __restrict__ covs,
                                  const float* __restrict__ colors,
                                  const float* __restrict__ extr,
                                  const int*   __restrict__ img_ids,
                                  float4* __restrict__ AB,
                                  int n_imgs) {
    int idx = blockIdx.x * blockDim.x + threadIdx.x;
    if (idx >= n_imgs * N_GAUSS) return;
    const int img = idx / N_GAUSS;
    const int g   = idx - img * N_GAUSS;

    const float mx = means[3 * g + 0];
    const float my = means[3 * g + 1];
    const float mz = means[3 * g + 2];
    const float* c = covs + 9 * g;
    const float s2  = (c[0] + c[4] + c[8]) * (1.0f / 3.0f);
    const float sig = sqrtf(s2);                 // match reference rounding
    const float kg2 = -0.5f * LOG2E / (sig * sig + EPS);

    const int cam = img_ids[img];
    const float* E = extr + 16 * cam;
    const float ox = E[3], oy = E[7], oz = E[11];
    const float ux = mx - ox, uy = my - oy, uz = mz - oz;
    const float n2c = ux * ux + uy * uy + uz * uz;

    AB[2 * idx + 0] = make_float4(mx, my, mz, kg2);
    AB[2 * idx + 1] = make_float4(colors[3 * g + 0], colors[3 * g + 1],
                                  colors[3 * g + 2], kg2 * n2c);
}

// grid: (NPIX/256, SPLIT, n_imgs), block 256. One thread = one pixel.
// Gaussian data read at wave-uniform addresses (scalar-load path), no LDS.
__global__ __launch_bounds__(256, 8) void render_kernel(
        const float4* __restrict__ AB,
        const float*  __restrict__ intr,
        const float*  __restrict__ extr,
        const int*    __restrict__ img_ids,
        float4*       __restrict__ partial,
        int n_imgs) {
    const int tid   = threadIdx.x;
    const int split = blockIdx.y;
    const int img   = blockIdx.z;

    const int cam = img_ids[img];
    const float* I = intr + 4 * cam;
    const float* E = extr + 16 * cam;
    const float fx = I[0], fy = I[1], cx = I[2], cy = I[3];

    const int pixel = blockIdx.x * 256 + tid;
    const int row = pixel >> 6;
    const int col = pixel & 63;

    const float d0 = ((float)col - cx) / fx;
    const float d1 = -(((float)row) - cy) / fy;
    const float d2 = -1.0f;
    const float rdx = d0 * E[0] + d1 * E[1] + d2 * E[2];
    const float rdy = d0 * E[4] + d1 * E[5] + d2 * E[6];
    const float rdz = d0 * E[8] + d1 * E[9] + d2 * E[10];
    const float ox = E[3], oy = E[7], oz = E[11];

    const float dd2 = rdx * rdx + rdy * rdy + rdz * rdz - 2.0f;
    const float mod = -(ox * rdx + oy * rdy + oz * rdz);   // -(o.d)

    const float4* __restrict__ base = AB + 2 * (img * N_GAUSS + split * GPS);

    float wsum = 0.0f, cr = 0.0f, cg = 0.0f, cb = 0.0f;
    #pragma unroll 8
    for (int g = 0; g < GPS; g++) {
        const float4 a = base[2 * g + 0];
        const float4 b = base[2 * g + 1];
        const float t  = fmaf(a.x, rdx, fmaf(a.y, rdy, fmaf(a.z, rdz, mod)));
        const float q  = a.w * (t * t);
        const float w  = __builtin_amdgcn_exp2f(fmaf(q, dd2, b.w));
        wsum += w;
        cr = fmaf(w, b.x, cr);
        cg = fmaf(w, b.y, cg);
        cb = fmaf(w, b.z, cb);
    }

    const int idx = img * NPIX + pixel;
    partial[split * (n_imgs * NPIX) + idx] = make_float4(wsum, cr, cg, cb);
}

__global__ void reduce_kernel(const float4* __restrict__ partial,
                              float* __restrict__ out,
                              int n_imgs) {
    const int idx = blockIdx.x * blockDim.x + threadIdx.x;
    const int total = n_imgs * NPIX;
    if (idx >= total) return;
    float w = 0.0f, r = 0.0f, g = 0.0f, b = 0.0f;
    #pragma unroll 8
    for (int s = 0; s < SPLIT; s++) {
        const float4 p = partial[s * total + idx];
        w += p.x; r += p.y; g += p.z; b += p.w;
    }
    const float inv = 1.0f / (w + EPS);
    const int img = idx >> 12;        // / NPIX
    const int pix = idx & (NPIX - 1);
    out[(img * 3 + 0) * NPIX + pix] = r * inv;
    out[(img * 3 + 1) * NPIX + pix] = g * inv;
    out[(img * 3 + 2) * NPIX + pix] = b * inv;
}

extern "C" void kernel_launch(void* const* d_in, const int* in_sizes, int n_in,
                              void* d_out, int out_size, void* d_ws, size_t ws_size,
                              hipStream_t stream) {
    const float* means   = (const float*)d_in[0];
    const float* covs    = (const float*)d_in[1];
    const float* colors  = (const float*)d_in[2];
    const float* intr    = (const float*)d_in[3];
    const float* extr    = (const float*)d_in[4];
    const int*   img_ids = (const int*)d_in[5];
    float* out = (float*)d_out;
    const int n_imgs = in_sizes[5];

    // ws layout: AB[2 * n_imgs * N_GAUSS] | partial[SPLIT * n_imgs * NPIX]
    float4* AB      = (float4*)d_ws;
    float4* partial = AB + 2 * n_imgs * N_GAUSS;

    const int npre = n_imgs * N_GAUSS;
    precompute_kernel<<<(npre + 255) / 256, 256, 0, stream>>>(
        means, covs, colors, extr, img_ids, AB, n_imgs);

    dim3 grid(NPIX / 256, SPLIT, n_imgs);
    render_kernel<<<grid, 256, 0, stream>>>(AB, intr, extr, img_ids, partial, n_imgs);

    const int total = n_imgs * NPIX;
    reduce_kernel<<<(total + 255) / 256, 256, 0, stream>>>(partial, out, n_imgs);
}